// Round 1
// baseline (1941.484 us; speedup 1.0000x reference)
//
#include <hip/hip_runtime.h>

#define N_NODES 100000
#define N_EDGES 3200000
#define IN_CH 128
#define HID 64
#define N_GRAPHS 512

// ---------------------------------------------------------------------------
// deg[dst] += 1 over all edges (float atomics; counts < 2^24 so exact)
__global__ __launch_bounds__(256) void deg_kernel(const int* __restrict__ dst,
                                                  float* __restrict__ deg) {
    int e = blockIdx.x * 256 + threadIdx.x;
    if (e < N_EDGES) atomicAdd(&deg[dst[e]], 1.0f);
}

// dis[i] = rsqrt(deg[i] + 1)   (in place)
__global__ __launch_bounds__(256) void dis_kernel(float* __restrict__ deg) {
    int i = blockIdx.x * 256 + threadIdx.x;
    if (i < N_NODES) deg[i] = rsqrtf(deg[i] + 1.0f);
}

// ---------------------------------------------------------------------------
// Y[M,64] = (RELU ? relu(X) : X)[M,K] @ W[K,64]
// block = 256 threads, 32 rows/block; thread t -> row t>>3, channels (t&7)*8..+8
template<int K, bool RELU>
__global__ __launch_bounds__(256) void gemm_kernel(const float* __restrict__ X,
                                                   const float* __restrict__ W,
                                                   float* __restrict__ Y) {
    __shared__ float Wl[K * 64];
    int t = threadIdx.x;
    for (int idx = t; idx < K * 64; idx += 256) Wl[idx] = W[idx];
    __syncthreads();

    int row = blockIdx.x * 32 + (t >> 3);
    if (row >= N_NODES) return;
    int c0 = (t & 7) * 8;

    float acc[8] = {0.f, 0.f, 0.f, 0.f, 0.f, 0.f, 0.f, 0.f};
    const float* xr = X + (size_t)row * K;
#pragma unroll 8
    for (int k = 0; k < K; k += 4) {
        float4 xv = *reinterpret_cast<const float4*>(xr + k);
        if (RELU) {
            xv.x = fmaxf(xv.x, 0.f); xv.y = fmaxf(xv.y, 0.f);
            xv.z = fmaxf(xv.z, 0.f); xv.w = fmaxf(xv.w, 0.f);
        }
        float xk[4] = {xv.x, xv.y, xv.z, xv.w};
#pragma unroll
        for (int kk = 0; kk < 4; ++kk) {
            const float4 w0 = *reinterpret_cast<const float4*>(&Wl[(k + kk) * 64 + c0]);
            const float4 w1 = *reinterpret_cast<const float4*>(&Wl[(k + kk) * 64 + c0 + 4]);
            acc[0] += xk[kk] * w0.x; acc[1] += xk[kk] * w0.y;
            acc[2] += xk[kk] * w0.z; acc[3] += xk[kk] * w0.w;
            acc[4] += xk[kk] * w1.x; acc[5] += xk[kk] * w1.y;
            acc[6] += xk[kk] * w1.z; acc[7] += xk[kk] * w1.w;
        }
    }
    float* yr = Y + (size_t)row * 64 + c0;
    *reinterpret_cast<float4*>(yr)     = make_float4(acc[0], acc[1], acc[2], acc[3]);
    *reinterpret_cast<float4*>(yr + 4) = make_float4(acc[4], acc[5], acc[6], acc[7]);
}

// ---------------------------------------------------------------------------
// B[i][c] = A[i][c] * dis[i]^2 + b[c]   (self-loop term + bias; also inits B)
__global__ __launch_bounds__(256) void init_kernel(const float* __restrict__ A,
                                                   const float* __restrict__ dis,
                                                   const float* __restrict__ b,
                                                   float* __restrict__ B) {
    int idx = blockIdx.x * 256 + threadIdx.x;   // over N_NODES*64 = 6.4M
    int i = idx >> 6, c = idx & 63;
    float d = dis[i];
    B[idx] = A[idx] * d * d + b[c];
}

// ---------------------------------------------------------------------------
// per edge e: B[dst[e]][c] += A[src[e]][c] * dis[src]*dis[dst], lane = channel
__global__ __launch_bounds__(256) void scatter_kernel(const int* __restrict__ src,
                                                      const int* __restrict__ dst,
                                                      const float* __restrict__ dis,
                                                      const float* __restrict__ A,
                                                      float* __restrict__ B) {
    int e = blockIdx.x * 4 + (threadIdx.x >> 6);
    int lane = threadIdx.x & 63;
    if (e >= N_EDGES) return;
    int s = src[e];
    int d = dst[e];
    float norm = dis[s] * dis[d];
    float v = A[(size_t)s * 64 + lane] * norm;
    atomicAdd(&B[(size_t)d * 64 + lane], v);
}

// ---------------------------------------------------------------------------
// pooled sums + counts (relu fused on read)
__global__ __launch_bounds__(256) void pool_kernel(const float* __restrict__ B,
                                                   const int* __restrict__ batch,
                                                   float* __restrict__ sums,
                                                   float* __restrict__ cnt) {
    int i = blockIdx.x * 4 + (threadIdx.x >> 6);
    int lane = threadIdx.x & 63;
    if (i >= N_NODES) return;
    int g = batch[i];
    float v = fmaxf(B[(size_t)i * 64 + lane], 0.f);
    atomicAdd(&sums[g * 64 + lane], v);
    if (lane == 0) atomicAdd(&cnt[g], 1.0f);
}

__global__ __launch_bounds__(256) void final_kernel(const float* __restrict__ sums,
                                                    const float* __restrict__ cnt,
                                                    float* __restrict__ out) {
    int idx = blockIdx.x * 256 + threadIdx.x;
    if (idx < N_GRAPHS * 64) out[idx] = sums[idx] / fmaxf(cnt[idx >> 6], 1.0f);
}

// ---------------------------------------------------------------------------
extern "C" void kernel_launch(void* const* d_in, const int* in_sizes, int n_in,
                              void* d_out, int out_size, void* d_ws, size_t ws_size,
                              hipStream_t stream) {
    const float* x     = (const float*)d_in[0];
    const int*   edge  = (const int*)d_in[1];   // [2, E]: row0 = src, row1 = dst
    const int*   batch = (const int*)d_in[2];
    const float* W1    = (const float*)d_in[3];
    const float* b1    = (const float*)d_in[4];
    const float* W2    = (const float*)d_in[5];
    const float* b2    = (const float*)d_in[6];
    float* out = (float*)d_out;

    // workspace layout (floats)
    float* A    = (float*)d_ws;                    // 6,400,000
    float* B    = A + (size_t)N_NODES * 64;        // 6,400,000
    float* dis  = B + (size_t)N_NODES * 64;        // 100,000 (deg -> rsqrt in place)
    float* sums = dis + N_NODES;                   // 32,768
    float* cnt  = sums + (size_t)N_GRAPHS * 64;    // 512

    const int* src = edge;
    const int* dst = edge + N_EDGES;

    hipMemsetAsync(dis, 0, N_NODES * sizeof(float), stream);
    hipMemsetAsync(sums, 0, (N_GRAPHS * 64 + N_GRAPHS) * sizeof(float), stream);

    deg_kernel<<<(N_EDGES + 255) / 256, 256, 0, stream>>>(dst, dis);
    dis_kernel<<<(N_NODES + 255) / 256, 256, 0, stream>>>(dis);

    // layer 1
    gemm_kernel<IN_CH, false><<<(N_NODES + 31) / 32, 256, 0, stream>>>(x, W1, A);
    init_kernel<<<(N_NODES * 64) / 256, 256, 0, stream>>>(A, dis, b1, B);
    scatter_kernel<<<(N_EDGES + 3) / 4, 256, 0, stream>>>(src, dst, dis, A, B);

    // layer 2 (relu of B fused into GEMM read)
    gemm_kernel<HID, true><<<(N_NODES + 31) / 32, 256, 0, stream>>>(B, W2, A);
    init_kernel<<<(N_NODES * 64) / 256, 256, 0, stream>>>(A, dis, b2, B);
    scatter_kernel<<<(N_EDGES + 3) / 4, 256, 0, stream>>>(src, dst, dis, A, B);

    // pool (relu fused) + finalize
    pool_kernel<<<(N_NODES + 3) / 4, 256, 0, stream>>>(B, batch, sums, cnt);
    final_kernel<<<(N_GRAPHS * 64 + 255) / 256, 256, 0, stream>>>(sums, cnt, out);
}

// Round 2
// 1029.139 us; speedup vs baseline: 1.8865x; 1.8865x over previous
//
#include <hip/hip_runtime.h>

#define N_NODES 100000
#define N_EDGES 3200000
#define IN_CH 128
#define HID 64
#define N_GRAPHS 512
#define SCAN_BLOCKS ((N_NODES + 255) / 256)   // 391

// ---------------------------------------------------------------------------
// histogram of in-degree (int atomics on 400 KB counter array)
__global__ __launch_bounds__(256) void hist_kernel(const int* __restrict__ dst,
                                                   int* __restrict__ cnt) {
    int e = blockIdx.x * 256 + threadIdx.x;
    if (e < N_EDGES) atomicAdd(&cnt[dst[e]], 1);
}

// dis[i] = rsqrt(cnt[i] + 1)
__global__ __launch_bounds__(256) void dis_kernel(const int* __restrict__ cnt,
                                                  float* __restrict__ dis) {
    int i = blockIdx.x * 256 + threadIdx.x;
    if (i < N_NODES) dis[i] = rsqrtf((float)cnt[i] + 1.0f);
}

// ---------------------------------------------------------------------------
// 3-kernel exclusive scan over cnt[N_NODES] -> row_ptr (+ cursor copy)
__global__ __launch_bounds__(256) void scanA_kernel(const int* __restrict__ cnt,
                                                    int* __restrict__ row_ptr,
                                                    int* __restrict__ block_sums) {
    __shared__ int s[256];
    int t = threadIdx.x;
    int idx = blockIdx.x * 256 + t;
    int v = (idx < N_NODES) ? cnt[idx] : 0;
    s[t] = v;
    __syncthreads();
#pragma unroll
    for (int o = 1; o < 256; o <<= 1) {
        int x = (t >= o) ? s[t - o] : 0;
        __syncthreads();
        s[t] += x;
        __syncthreads();
    }
    if (idx < N_NODES) row_ptr[idx] = s[t] - v;          // exclusive
    if (t == 255) block_sums[blockIdx.x] = s[255];
}

__global__ __launch_bounds__(512) void scanB_kernel(int* __restrict__ block_sums) {
    __shared__ int s[512];
    int t = threadIdx.x;
    int v = (t < SCAN_BLOCKS) ? block_sums[t] : 0;
    s[t] = v;
    __syncthreads();
#pragma unroll
    for (int o = 1; o < 512; o <<= 1) {
        int x = (t >= o) ? s[t - o] : 0;
        __syncthreads();
        s[t] += x;
        __syncthreads();
    }
    if (t < SCAN_BLOCKS) block_sums[t] = s[t] - v;       // exclusive
}

__global__ __launch_bounds__(256) void scanC_kernel(int* __restrict__ row_ptr,
                                                    const int* __restrict__ block_sums,
                                                    int* __restrict__ cursor) {
    int idx = blockIdx.x * 256 + threadIdx.x;
    if (idx < N_NODES) {
        int r = row_ptr[idx] + block_sums[blockIdx.x];
        row_ptr[idx] = r;
        cursor[idx] = r;
    }
    if (idx == 0) row_ptr[N_NODES] = N_EDGES;
}

// csr_src[cursor[dst]++] = src
__global__ __launch_bounds__(256) void fill_kernel(const int* __restrict__ src,
                                                   const int* __restrict__ dst,
                                                   int* __restrict__ cursor,
                                                   int* __restrict__ csr_src) {
    int e = blockIdx.x * 256 + threadIdx.x;
    if (e < N_EDGES) {
        int p = atomicAdd(&cursor[dst[e]], 1);
        csr_src[p] = src[e];
    }
}

// ---------------------------------------------------------------------------
// Y[M,64] = (RELU?relu(X):X)[M,K] @ W[K,64], scaled by dis[row] (epilogue)
// block = 256 threads, 32 rows/block; thread t -> row t>>3, channels (t&7)*8..+8
template<int K, bool RELU>
__global__ __launch_bounds__(256) void gemm_kernel(const float* __restrict__ X,
                                                   const float* __restrict__ W,
                                                   const float* __restrict__ dis,
                                                   float* __restrict__ Y) {
    __shared__ float Wl[K * 64];
    int t = threadIdx.x;
    for (int idx = t; idx < K * 64; idx += 256) Wl[idx] = W[idx];
    __syncthreads();

    int row = blockIdx.x * 32 + (t >> 3);
    if (row >= N_NODES) return;
    int c0 = (t & 7) * 8;

    float acc[8] = {0.f, 0.f, 0.f, 0.f, 0.f, 0.f, 0.f, 0.f};
    const float* xr = X + (size_t)row * K;
#pragma unroll 8
    for (int k = 0; k < K; k += 4) {
        float4 xv = *reinterpret_cast<const float4*>(xr + k);
        if (RELU) {
            xv.x = fmaxf(xv.x, 0.f); xv.y = fmaxf(xv.y, 0.f);
            xv.z = fmaxf(xv.z, 0.f); xv.w = fmaxf(xv.w, 0.f);
        }
        float xk[4] = {xv.x, xv.y, xv.z, xv.w};
#pragma unroll
        for (int kk = 0; kk < 4; ++kk) {
            const float4 w0 = *reinterpret_cast<const float4*>(&Wl[(k + kk) * 64 + c0]);
            const float4 w1 = *reinterpret_cast<const float4*>(&Wl[(k + kk) * 64 + c0 + 4]);
            acc[0] += xk[kk] * w0.x; acc[1] += xk[kk] * w0.y;
            acc[2] += xk[kk] * w0.z; acc[3] += xk[kk] * w0.w;
            acc[4] += xk[kk] * w1.x; acc[5] += xk[kk] * w1.y;
            acc[6] += xk[kk] * w1.z; acc[7] += xk[kk] * w1.w;
        }
    }
    float d = dis[row];
    float* yr = Y + (size_t)row * 64 + c0;
    *reinterpret_cast<float4*>(yr) =
        make_float4(acc[0] * d, acc[1] * d, acc[2] * d, acc[3] * d);
    *reinterpret_cast<float4*>(yr + 4) =
        make_float4(acc[4] * d, acc[5] * d, acc[6] * d, acc[7] * d);
}

// ---------------------------------------------------------------------------
// wave per node: B[i] = b + dis[i] * (A'[i] + sum_{s in in(i)} A'[s])
// where A' = (X@W)*dis (prescaled in GEMM epilogue). lane = channel.
__global__ __launch_bounds__(256) void gather_kernel(const int* __restrict__ row_ptr,
                                                     const int* __restrict__ csr_src,
                                                     const float* __restrict__ dis,
                                                     const float* __restrict__ bias,
                                                     const float* __restrict__ A,
                                                     float* __restrict__ B) {
    int i = blockIdx.x * 4 + (threadIdx.x >> 6);
    int lane = threadIdx.x & 63;
    if (i >= N_NODES) return;
    int e = row_ptr[i];
    int end = row_ptr[i + 1];
    float acc = A[(size_t)i * 64 + lane];          // self term (already *dis[i])
    for (; e + 4 <= end; e += 4) {
        int s0 = csr_src[e], s1 = csr_src[e + 1];
        int s2 = csr_src[e + 2], s3 = csr_src[e + 3];
        float v0 = A[(size_t)s0 * 64 + lane];
        float v1 = A[(size_t)s1 * 64 + lane];
        float v2 = A[(size_t)s2 * 64 + lane];
        float v3 = A[(size_t)s3 * 64 + lane];
        acc += (v0 + v1) + (v2 + v3);
    }
    for (; e < end; ++e) acc += A[(size_t)csr_src[e] * 64 + lane];
    B[(size_t)i * 64 + lane] = bias[lane] + dis[i] * acc;
}

// ---------------------------------------------------------------------------
__global__ __launch_bounds__(256) void pool_kernel(const float* __restrict__ B,
                                                   const int* __restrict__ batch,
                                                   float* __restrict__ sums,
                                                   float* __restrict__ cnt) {
    int i = blockIdx.x * 4 + (threadIdx.x >> 6);
    int lane = threadIdx.x & 63;
    if (i >= N_NODES) return;
    int g = batch[i];
    float v = fmaxf(B[(size_t)i * 64 + lane], 0.f);
    atomicAdd(&sums[g * 64 + lane], v);
    if (lane == 0) atomicAdd(&cnt[g], 1.0f);
}

__global__ __launch_bounds__(256) void final_kernel(const float* __restrict__ sums,
                                                    const float* __restrict__ cnt,
                                                    float* __restrict__ out) {
    int idx = blockIdx.x * 256 + threadIdx.x;
    if (idx < N_GRAPHS * 64) out[idx] = sums[idx] / fmaxf(cnt[idx >> 6], 1.0f);
}

// ---------------------------------------------------------------------------
extern "C" void kernel_launch(void* const* d_in, const int* in_sizes, int n_in,
                              void* d_out, int out_size, void* d_ws, size_t ws_size,
                              hipStream_t stream) {
    const float* x     = (const float*)d_in[0];
    const int*   edge  = (const int*)d_in[1];   // [2, E]: row0 = src, row1 = dst
    const int*   batch = (const int*)d_in[2];
    const float* W1    = (const float*)d_in[3];
    const float* b1    = (const float*)d_in[4];
    const float* W2    = (const float*)d_in[5];
    const float* b2    = (const float*)d_in[6];
    float* out = (float*)d_out;

    // workspace layout
    float* A        = (float*)d_ws;                       // 6,400,000 f
    float* B        = A + (size_t)N_NODES * 64;           // 6,400,000 f
    float* dis      = B + (size_t)N_NODES * 64;           // 100,000 f
    float* sums     = dis + N_NODES;                      // 32,768 f
    float* cnt_f    = sums + (size_t)N_GRAPHS * 64;       // 512 f
    int*   cnt      = (int*)(cnt_f + N_GRAPHS);           // 100,000 i
    int*   row_ptr  = cnt + N_NODES;                      // 100,001 i
    int*   cursor   = row_ptr + N_NODES + 1;              // 100,000 i
    int*   blk_sums = cursor + N_NODES;                   // 512 i
    int*   csr_src  = blk_sums + 512;                     // 3,200,000 i
    // total ~66 MB

    const int* src = edge;
    const int* dst = edge + N_EDGES;

    hipMemsetAsync(cnt, 0, N_NODES * sizeof(int), stream);
    hipMemsetAsync(sums, 0, (N_GRAPHS * 64 + N_GRAPHS) * sizeof(float), stream);

    // CSR build
    hist_kernel<<<(N_EDGES + 255) / 256, 256, 0, stream>>>(dst, cnt);
    dis_kernel<<<(N_NODES + 255) / 256, 256, 0, stream>>>(cnt, dis);
    scanA_kernel<<<SCAN_BLOCKS, 256, 0, stream>>>(cnt, row_ptr, blk_sums);
    scanB_kernel<<<1, 512, 0, stream>>>(blk_sums);
    scanC_kernel<<<SCAN_BLOCKS, 256, 0, stream>>>(row_ptr, blk_sums, cursor);
    fill_kernel<<<(N_EDGES + 255) / 256, 256, 0, stream>>>(src, dst, cursor, csr_src);

    // layer 1: A = (x@W1)*dis ; B = b1 + dis*(A[i] + sum A[src])
    gemm_kernel<IN_CH, false><<<(N_NODES + 31) / 32, 256, 0, stream>>>(x, W1, dis, A);
    gather_kernel<<<(N_NODES + 3) / 4, 256, 0, stream>>>(row_ptr, csr_src, dis, b1, A, B);

    // layer 2 (relu fused into GEMM read)
    gemm_kernel<HID, true><<<(N_NODES + 31) / 32, 256, 0, stream>>>(B, W2, dis, A);
    gather_kernel<<<(N_NODES + 3) / 4, 256, 0, stream>>>(row_ptr, csr_src, dis, b2, A, B);

    // pool (relu fused) + finalize
    pool_kernel<<<(N_NODES + 3) / 4, 256, 0, stream>>>(B, batch, sums, cnt_f);
    final_kernel<<<(N_GRAPHS * 64 + 255) / 256, 256, 0, stream>>>(sums, cnt_f, out);
}

// Round 3
// 701.056 us; speedup vs baseline: 2.7694x; 1.4680x over previous
//
#include <hip/hip_runtime.h>

#define N_NODES 100000
#define N_EDGES 3200000
#define IN_CH 128
#define HID 64
#define N_GRAPHS 512
#define SCAN_BLOCKS ((N_NODES + 255) / 256)       // 391
#define EPB 4096                                   // edges per block (binning)
#define NBLK ((N_EDGES + EPB - 1) / EPB)           // 782
#define NB 196                                     // buckets = dst>>9 (512 nodes)

// ---------------------------------------------------------------------------
// P1: per-block bucket histogram (LDS) + global node in-degree (fused)
__global__ __launch_bounds__(256) void binhist_kernel(const int* __restrict__ dst,
                                                      int* __restrict__ cnt,
                                                      int* __restrict__ hist_g) {
    __shared__ int h[NB];
    for (int i = threadIdx.x; i < NB; i += 256) h[i] = 0;
    __syncthreads();
    int base = blockIdx.x * EPB;
    int end = min(base + EPB, N_EDGES);
    for (int e = base + threadIdx.x; e < end; e += 256) {
        int d = dst[e];
        atomicAdd(&cnt[d], 1);
        atomicAdd(&h[d >> 9], 1);
    }
    __syncthreads();
    for (int b = threadIdx.x; b < NB; b += 256) hist_g[b * NBLK + blockIdx.x] = h[b];
}

// S1: per bucket, exclusive scan across blocks (in place), total per bucket
__global__ __launch_bounds__(256) void s1_kernel(int* __restrict__ hist_g,
                                                 int* __restrict__ total) {
    __shared__ int buf[NBLK];
    int b = blockIdx.x;
    for (int j = threadIdx.x; j < NBLK; j += 256) buf[j] = hist_g[b * NBLK + j];
    __syncthreads();
    if (threadIdx.x == 0) {
        int run = 0;
        for (int j = 0; j < NBLK; ++j) { int v = buf[j]; buf[j] = run; run += v; }
        total[b] = run;
    }
    __syncthreads();
    for (int j = threadIdx.x; j < NBLK; j += 256) hist_g[b * NBLK + j] = buf[j];
}

// S2: exclusive scan of bucket totals -> bucket bases
__global__ __launch_bounds__(256) void s2_kernel(const int* __restrict__ total,
                                                 int* __restrict__ bbase) {
    __shared__ int s[256];
    int t = threadIdx.x;
    int v = (t < NB) ? total[t] : 0;
    s[t] = v;
    __syncthreads();
#pragma unroll
    for (int o = 1; o < 256; o <<= 1) {
        int x = (t >= o) ? s[t - o] : 0;
        __syncthreads();
        s[t] += x;
        __syncthreads();
    }
    if (t < NB) bbase[t] = s[t] - v;
}

// P3: multisplit — write (src,dst) pairs bucket-contiguously
__global__ __launch_bounds__(256) void binscatter_kernel(const int* __restrict__ src,
                                                         const int* __restrict__ dst,
                                                         const int* __restrict__ hist_g,
                                                         const int* __restrict__ bbase,
                                                         int2* __restrict__ pairs) {
    __shared__ int cur[NB];
    __shared__ int start[NB];
    for (int i = threadIdx.x; i < NB; i += 256) {
        cur[i] = 0;
        start[i] = bbase[i] + hist_g[i * NBLK + blockIdx.x];
    }
    __syncthreads();
    int base = blockIdx.x * EPB;
    int end = min(base + EPB, N_EDGES);
    for (int e = base + threadIdx.x; e < end; e += 256) {
        int s = src[e], d = dst[e];
        int b = d >> 9;
        int r = atomicAdd(&cur[b], 1);
        pairs[start[b] + r] = make_int2(s, d);
    }
}

// P4: local fill — pairs are bucket-sorted, cursor/csr writes are L2-local
__global__ __launch_bounds__(256) void fill2_kernel(const int2* __restrict__ pairs,
                                                    int* __restrict__ cursor,
                                                    int* __restrict__ csr_src) {
    int base = blockIdx.x * EPB;
    int end = min(base + EPB, N_EDGES);
    for (int e = base + threadIdx.x; e < end; e += 256) {
        int2 p = pairs[e];
        int pos = atomicAdd(&cursor[p.y], 1);
        csr_src[pos] = p.x;
    }
}

// ---------------------------------------------------------------------------
// dis[i] = rsqrt(cnt[i] + 1)
__global__ __launch_bounds__(256) void dis_kernel(const int* __restrict__ cnt,
                                                  float* __restrict__ dis) {
    int i = blockIdx.x * 256 + threadIdx.x;
    if (i < N_NODES) dis[i] = rsqrtf((float)cnt[i] + 1.0f);
}

// 3-kernel exclusive scan over cnt[N_NODES] -> row_ptr (+ cursor copy)
__global__ __launch_bounds__(256) void scanA_kernel(const int* __restrict__ cnt,
                                                    int* __restrict__ row_ptr,
                                                    int* __restrict__ block_sums) {
    __shared__ int s[256];
    int t = threadIdx.x;
    int idx = blockIdx.x * 256 + t;
    int v = (idx < N_NODES) ? cnt[idx] : 0;
    s[t] = v;
    __syncthreads();
#pragma unroll
    for (int o = 1; o < 256; o <<= 1) {
        int x = (t >= o) ? s[t - o] : 0;
        __syncthreads();
        s[t] += x;
        __syncthreads();
    }
    if (idx < N_NODES) row_ptr[idx] = s[t] - v;
    if (t == 255) block_sums[blockIdx.x] = s[255];
}

__global__ __launch_bounds__(512) void scanB_kernel(int* __restrict__ block_sums) {
    __shared__ int s[512];
    int t = threadIdx.x;
    int v = (t < SCAN_BLOCKS) ? block_sums[t] : 0;
    s[t] = v;
    __syncthreads();
#pragma unroll
    for (int o = 1; o < 512; o <<= 1) {
        int x = (t >= o) ? s[t - o] : 0;
        __syncthreads();
        s[t] += x;
        __syncthreads();
    }
    if (t < SCAN_BLOCKS) block_sums[t] = s[t] - v;
}

__global__ __launch_bounds__(256) void scanC_kernel(int* __restrict__ row_ptr,
                                                    const int* __restrict__ block_sums,
                                                    int* __restrict__ cursor) {
    int idx = blockIdx.x * 256 + threadIdx.x;
    if (idx < N_NODES) {
        int r = row_ptr[idx] + block_sums[blockIdx.x];
        row_ptr[idx] = r;
        cursor[idx] = r;
    }
    if (idx == 0) row_ptr[N_NODES] = N_EDGES;
}

// ---------------------------------------------------------------------------
// Y[M,64] = (RELU?relu(X):X)[M,K] @ W[K,64], scaled by dis[row]
template<int K, bool RELU>
__global__ __launch_bounds__(256) void gemm_kernel(const float* __restrict__ X,
                                                   const float* __restrict__ W,
                                                   const float* __restrict__ dis,
                                                   float* __restrict__ Y) {
    __shared__ float Wl[K * 64];
    int t = threadIdx.x;
    for (int idx = t; idx < K * 64; idx += 256) Wl[idx] = W[idx];
    __syncthreads();

    int row = blockIdx.x * 32 + (t >> 3);
    if (row >= N_NODES) return;
    int c0 = (t & 7) * 8;

    float acc[8] = {0.f, 0.f, 0.f, 0.f, 0.f, 0.f, 0.f, 0.f};
    const float* xr = X + (size_t)row * K;
#pragma unroll 8
    for (int k = 0; k < K; k += 4) {
        float4 xv = *reinterpret_cast<const float4*>(xr + k);
        if (RELU) {
            xv.x = fmaxf(xv.x, 0.f); xv.y = fmaxf(xv.y, 0.f);
            xv.z = fmaxf(xv.z, 0.f); xv.w = fmaxf(xv.w, 0.f);
        }
        float xk[4] = {xv.x, xv.y, xv.z, xv.w};
#pragma unroll
        for (int kk = 0; kk < 4; ++kk) {
            const float4 w0 = *reinterpret_cast<const float4*>(&Wl[(k + kk) * 64 + c0]);
            const float4 w1 = *reinterpret_cast<const float4*>(&Wl[(k + kk) * 64 + c0 + 4]);
            acc[0] += xk[kk] * w0.x; acc[1] += xk[kk] * w0.y;
            acc[2] += xk[kk] * w0.z; acc[3] += xk[kk] * w0.w;
            acc[4] += xk[kk] * w1.x; acc[5] += xk[kk] * w1.y;
            acc[6] += xk[kk] * w1.z; acc[7] += xk[kk] * w1.w;
        }
    }
    float d = dis[row];
    float* yr = Y + (size_t)row * 64 + c0;
    *reinterpret_cast<float4*>(yr) =
        make_float4(acc[0] * d, acc[1] * d, acc[2] * d, acc[3] * d);
    *reinterpret_cast<float4*>(yr + 4) =
        make_float4(acc[4] * d, acc[5] * d, acc[6] * d, acc[7] * d);
}

// ---------------------------------------------------------------------------
// wave per node, float2 per lane, 2 edges per wave-step (4-edge unroll):
// B[i] = b + dis[i] * (A'[i] + sum A'[src]),  A' = (X@W)*dis
__global__ __launch_bounds__(256) void gather_kernel(const int* __restrict__ row_ptr,
                                                     const int* __restrict__ csr_src,
                                                     const float* __restrict__ dis,
                                                     const float* __restrict__ bias,
                                                     const float* __restrict__ A,
                                                     float* __restrict__ B) {
    int i = blockIdx.x * 4 + (threadIdx.x >> 6);
    if (i >= N_NODES) return;
    int lane = threadIdx.x & 63;
    int half = lane >> 5;            // which of 2 concurrent edges
    int c2 = (lane & 31) * 2;        // channel pair

    int e = row_ptr[i];
    int end = row_ptr[i + 1];

    float2 acc = make_float2(0.f, 0.f);
    if (!half) {                     // self term (already *dis[i])
        float2 v = *reinterpret_cast<const float2*>(&A[(size_t)i * 64 + c2]);
        acc.x = v.x; acc.y = v.y;
    }
    for (; e + 4 <= end; e += 4) {
        int s0 = csr_src[e + half];
        int s1 = csr_src[e + 2 + half];
        float2 v0 = *reinterpret_cast<const float2*>(&A[(size_t)s0 * 64 + c2]);
        float2 v1 = *reinterpret_cast<const float2*>(&A[(size_t)s1 * 64 + c2]);
        acc.x += v0.x + v1.x;
        acc.y += v0.y + v1.y;
    }
    for (; e + 2 <= end; e += 2) {
        int s = csr_src[e + half];
        float2 v = *reinterpret_cast<const float2*>(&A[(size_t)s * 64 + c2]);
        acc.x += v.x; acc.y += v.y;
    }
    if (e < end && !half) {
        int s = csr_src[e];
        float2 v = *reinterpret_cast<const float2*>(&A[(size_t)s * 64 + c2]);
        acc.x += v.x; acc.y += v.y;
    }
    acc.x += __shfl_xor(acc.x, 32);
    acc.y += __shfl_xor(acc.y, 32);
    if (!half) {
        float d = dis[i];
        float2 o;
        o.x = bias[c2] + d * acc.x;
        o.y = bias[c2 + 1] + d * acc.y;
        *reinterpret_cast<float2*>(&B[(size_t)i * 64 + c2]) = o;
    }
}

// ---------------------------------------------------------------------------
// pool: batch is sorted -> run-length accumulate per wave (32 nodes/wave)
__global__ __launch_bounds__(256) void pool_kernel(const float* __restrict__ B,
                                                   const int* __restrict__ batch,
                                                   float* __restrict__ sums,
                                                   float* __restrict__ cnt) {
    int w = blockIdx.x * 4 + (threadIdx.x >> 6);
    int lane = threadIdx.x & 63;
    int n0 = w * 32;
    if (n0 >= N_NODES) return;
    int n1 = min(n0 + 32, N_NODES);
    int curg = batch[n0];
    float acc = 0.f;
    int run = 0;
    for (int n = n0; n < n1; ++n) {
        int g = batch[n];
        if (g != curg) {
            atomicAdd(&sums[curg * 64 + lane], acc);
            if (lane == 0) atomicAdd(&cnt[curg], (float)run);
            curg = g; acc = 0.f; run = 0;
        }
        acc += fmaxf(B[(size_t)n * 64 + lane], 0.f);
        run++;
    }
    atomicAdd(&sums[curg * 64 + lane], acc);
    if (lane == 0) atomicAdd(&cnt[curg], (float)run);
}

__global__ __launch_bounds__(256) void final_kernel(const float* __restrict__ sums,
                                                    const float* __restrict__ cnt,
                                                    float* __restrict__ out) {
    int idx = blockIdx.x * 256 + threadIdx.x;
    if (idx < N_GRAPHS * 64) out[idx] = sums[idx] / fmaxf(cnt[idx >> 6], 1.0f);
}

// ---------------------------------------------------------------------------
extern "C" void kernel_launch(void* const* d_in, const int* in_sizes, int n_in,
                              void* d_out, int out_size, void* d_ws, size_t ws_size,
                              hipStream_t stream) {
    const float* x     = (const float*)d_in[0];
    const int*   edge  = (const int*)d_in[1];   // [2, E]: row0 = src, row1 = dst
    const int*   batch = (const int*)d_in[2];
    const float* W1    = (const float*)d_in[3];
    const float* b1    = (const float*)d_in[4];
    const float* W2    = (const float*)d_in[5];
    const float* b2    = (const float*)d_in[6];
    float* out = (float*)d_out;

    // workspace layout
    float* A        = (float*)d_ws;                       // 6,400,000 f (aliases pairs)
    float* B        = A + (size_t)N_NODES * 64;           // 6,400,000 f
    float* dis      = B + (size_t)N_NODES * 64;           // 100,000 f
    float* sums     = dis + N_NODES;                      // 32,768 f
    float* cnt_f    = sums + (size_t)N_GRAPHS * 64;       // 512 f
    int*   cnt      = (int*)(cnt_f + N_GRAPHS);           // 100,000 i
    int*   row_ptr  = cnt + N_NODES;                      // 100,001 i
    int*   cursor   = row_ptr + N_NODES + 1;              // 100,000 i
    int*   blk_sums = cursor + N_NODES;                   // 512 i
    int*   hist_g   = blk_sums + 512;                     // NB*NBLK = 153,272 i
    int*   total    = hist_g + NB * NBLK;                 // 196 i
    int*   bbase    = total + NB;                         // 196 i
    int*   csr_src  = bbase + NB;                         // 3,200,000 i
    int2*  pairs    = (int2*)A;                           // aliases A (dead until GEMM1)

    const int* src = edge;
    const int* dst = edge + N_EDGES;

    hipMemsetAsync(cnt, 0, N_NODES * sizeof(int), stream);
    hipMemsetAsync(sums, 0, (N_GRAPHS * 64 + N_GRAPHS) * sizeof(float), stream);

    // CSR build: binned counting sort (write-locality) + node-degree scan
    binhist_kernel<<<NBLK, 256, 0, stream>>>(dst, cnt, hist_g);
    dis_kernel<<<(N_NODES + 255) / 256, 256, 0, stream>>>(cnt, dis);
    s1_kernel<<<NB, 256, 0, stream>>>(hist_g, total);
    s2_kernel<<<1, 256, 0, stream>>>(total, bbase);
    scanA_kernel<<<SCAN_BLOCKS, 256, 0, stream>>>(cnt, row_ptr, blk_sums);
    scanB_kernel<<<1, 512, 0, stream>>>(blk_sums);
    scanC_kernel<<<SCAN_BLOCKS, 256, 0, stream>>>(row_ptr, blk_sums, cursor);
    binscatter_kernel<<<NBLK, 256, 0, stream>>>(src, dst, hist_g, bbase, pairs);
    fill2_kernel<<<NBLK, 256, 0, stream>>>(pairs, cursor, csr_src);

    // layer 1: A = (x@W1)*dis ; B = b1 + dis*(A[i] + sum A[src])
    gemm_kernel<IN_CH, false><<<(N_NODES + 31) / 32, 256, 0, stream>>>(x, W1, dis, A);
    gather_kernel<<<(N_NODES + 3) / 4, 256, 0, stream>>>(row_ptr, csr_src, dis, b1, A, B);

    // layer 2 (relu fused into GEMM read)
    gemm_kernel<HID, true><<<(N_NODES + 31) / 32, 256, 0, stream>>>(B, W2, dis, A);
    gather_kernel<<<(N_NODES + 3) / 4, 256, 0, stream>>>(row_ptr, csr_src, dis, b2, A, B);

    // pool (relu fused) + finalize
    pool_kernel<<<(N_NODES + 127) / 128, 256, 0, stream>>>(B, batch, sums, cnt_f);
    final_kernel<<<(N_GRAPHS * 64 + 255) / 256, 256, 0, stream>>>(sums, cnt_f, out);
}

// Round 4
// 471.290 us; speedup vs baseline: 4.1195x; 1.4875x over previous
//
#include <hip/hip_runtime.h>

#define N_NODES 100000
#define N_EDGES 3200000
#define IN_CH 128
#define HID 64
#define N_GRAPHS 512
#define EPB 4096                                   // edges per block (binning)
#define NBLK ((N_EDGES + EPB - 1) / EPB)           // 782
#define NB 391                                     // buckets = dst>>8 (256 nodes each)

// ---------------------------------------------------------------------------
// P1: per-block bucket histogram only (LDS, 4 replicated copies). NO global atomics.
__global__ __launch_bounds__(256) void binhist_kernel(const int* __restrict__ dst,
                                                      int* __restrict__ hist_g) {
    __shared__ int h[4 * NB];
    for (int i = threadIdx.x; i < 4 * NB; i += 256) h[i] = 0;
    __syncthreads();
    int w = threadIdx.x >> 6;          // wave id 0..3 -> histogram copy
    int base = blockIdx.x * EPB;
    int end = min(base + EPB, N_EDGES);
    for (int e = base + threadIdx.x; e < end; e += 256)
        atomicAdd(&h[w * NB + (dst[e] >> 8)], 1);
    __syncthreads();
    for (int b = threadIdx.x; b < NB; b += 256)
        hist_g[b * NBLK + blockIdx.x] = h[b] + h[NB + b] + h[2 * NB + b] + h[3 * NB + b];
}

// S1: per bucket, exclusive scan across blocks (in place), total per bucket
__global__ __launch_bounds__(256) void s1_kernel(int* __restrict__ hist_g,
                                                 int* __restrict__ total) {
    __shared__ int buf[NBLK];
    int b = blockIdx.x;
    for (int j = threadIdx.x; j < NBLK; j += 256) buf[j] = hist_g[b * NBLK + j];
    __syncthreads();
    if (threadIdx.x == 0) {
        int run = 0;
        for (int j = 0; j < NBLK; ++j) { int v = buf[j]; buf[j] = run; run += v; }
        total[b] = run;
    }
    __syncthreads();
    for (int j = threadIdx.x; j < NBLK; j += 256) hist_g[b * NBLK + j] = buf[j];
}

// S2: exclusive scan of bucket totals -> bucket bases (bbase has NB+1 entries)
__global__ __launch_bounds__(512) void s2_kernel(const int* __restrict__ total,
                                                 int* __restrict__ bbase) {
    __shared__ int s[512];
    int t = threadIdx.x;
    int v = (t < NB) ? total[t] : 0;
    s[t] = v;
    __syncthreads();
#pragma unroll
    for (int o = 1; o < 512; o <<= 1) {
        int x = (t >= o) ? s[t - o] : 0;
        __syncthreads();
        s[t] += x;
        __syncthreads();
    }
    if (t < NB) bbase[t] = s[t] - v;
    if (t == 0) bbase[NB] = N_EDGES;
}

// P3: multisplit — write (src,dst) pairs bucket-contiguously
__global__ __launch_bounds__(256) void binscatter_kernel(const int* __restrict__ src,
                                                         const int* __restrict__ dst,
                                                         const int* __restrict__ hist_g,
                                                         const int* __restrict__ bbase,
                                                         int2* __restrict__ pairs) {
    __shared__ int cur[NB];
    __shared__ int start[NB];
    for (int i = threadIdx.x; i < NB; i += 256) {
        cur[i] = 0;
        start[i] = bbase[i] + hist_g[i * NBLK + blockIdx.x];
    }
    __syncthreads();
    int base = blockIdx.x * EPB;
    int end = min(base + EPB, N_EDGES);
    for (int e = base + threadIdx.x; e < end; e += 256) {
        int s = src[e], d = dst[e];
        int b = d >> 8;
        int r = atomicAdd(&cur[b], 1);
        pairs[start[b] + r] = make_int2(s, d);
    }
}

// P4: fused per-bucket CSR build: LDS histogram -> LDS scan -> row_ptr/dis
//     (plain stores) -> LDS-cursor fill of csr_src (writes within ~32KB window).
__global__ __launch_bounds__(256) void bucket_csr_kernel(const int2* __restrict__ pairs,
                                                         const int* __restrict__ bbase,
                                                         int* __restrict__ csr_src,
                                                         int* __restrict__ row_ptr,
                                                         float* __restrict__ dis) {
    __shared__ int h[256];
    int b = blockIdx.x;
    int t = threadIdx.x;
    int e0 = bbase[b];
    int e1 = bbase[b + 1];
    h[t] = 0;
    __syncthreads();
    for (int e = e0 + t; e < e1; e += 256)
        atomicAdd(&h[pairs[e].y & 255], 1);
    __syncthreads();
    int v = h[t];                       // in-degree of node b*256+t
    // inclusive scan of h[256]
#pragma unroll
    for (int o = 1; o < 256; o <<= 1) {
        int x = (t >= o) ? h[t - o] : 0;
        __syncthreads();
        h[t] += x;
        __syncthreads();
    }
    int excl = h[t] - v;
    int n = b * 256 + t;
    if (n < N_NODES) {
        row_ptr[n] = e0 + excl;
        dis[n] = rsqrtf((float)v + 1.0f);
    }
    if (b == NB - 1 && t == 0) row_ptr[N_NODES] = N_EDGES;
    __syncthreads();
    h[t] = e0 + excl;                   // cursor
    __syncthreads();
    for (int e = e0 + t; e < e1; e += 256) {
        int2 p = pairs[e];
        int pos = atomicAdd(&h[p.y & 255], 1);
        csr_src[pos] = p.x;
    }
}

// ---------------------------------------------------------------------------
// Y[M,64] = (RELU?relu(X):X)[M,K] @ W[K,64], scaled by dis[row]
template<int K, bool RELU>
__global__ __launch_bounds__(256) void gemm_kernel(const float* __restrict__ X,
                                                   const float* __restrict__ W,
                                                   const float* __restrict__ dis,
                                                   float* __restrict__ Y) {
    __shared__ float Wl[K * 64];
    int t = threadIdx.x;
    for (int idx = t; idx < K * 64; idx += 256) Wl[idx] = W[idx];
    __syncthreads();

    int row = blockIdx.x * 32 + (t >> 3);
    if (row >= N_NODES) return;
    int c0 = (t & 7) * 8;

    float acc[8] = {0.f, 0.f, 0.f, 0.f, 0.f, 0.f, 0.f, 0.f};
    const float* xr = X + (size_t)row * K;
#pragma unroll 8
    for (int k = 0; k < K; k += 4) {
        float4 xv = *reinterpret_cast<const float4*>(xr + k);
        if (RELU) {
            xv.x = fmaxf(xv.x, 0.f); xv.y = fmaxf(xv.y, 0.f);
            xv.z = fmaxf(xv.z, 0.f); xv.w = fmaxf(xv.w, 0.f);
        }
        float xk[4] = {xv.x, xv.y, xv.z, xv.w};
#pragma unroll
        for (int kk = 0; kk < 4; ++kk) {
            const float4 w0 = *reinterpret_cast<const float4*>(&Wl[(k + kk) * 64 + c0]);
            const float4 w1 = *reinterpret_cast<const float4*>(&Wl[(k + kk) * 64 + c0 + 4]);
            acc[0] += xk[kk] * w0.x; acc[1] += xk[kk] * w0.y;
            acc[2] += xk[kk] * w0.z; acc[3] += xk[kk] * w0.w;
            acc[4] += xk[kk] * w1.x; acc[5] += xk[kk] * w1.y;
            acc[6] += xk[kk] * w1.z; acc[7] += xk[kk] * w1.w;
        }
    }
    float d = dis[row];
    float* yr = Y + (size_t)row * 64 + c0;
    *reinterpret_cast<float4*>(yr) =
        make_float4(acc[0] * d, acc[1] * d, acc[2] * d, acc[3] * d);
    *reinterpret_cast<float4*>(yr + 4) =
        make_float4(acc[4] * d, acc[5] * d, acc[6] * d, acc[7] * d);
}

// ---------------------------------------------------------------------------
// wave per node, 4 edges concurrent (16 lanes / edge, float4 per lane),
// 8-edge unroll with dual accumulators:
// B[i] = b + dis[i] * (A'[i] + sum A'[src]),  A' = (X@W)*dis
__global__ __launch_bounds__(256) void gather_kernel(const int* __restrict__ row_ptr,
                                                     const int* __restrict__ csr_src,
                                                     const float* __restrict__ dis,
                                                     const float* __restrict__ bias,
                                                     const float* __restrict__ A,
                                                     float* __restrict__ B) {
    int i = blockIdx.x * 4 + (threadIdx.x >> 6);
    if (i >= N_NODES) return;
    int lane = threadIdx.x & 63;
    int q = lane >> 4;               // which of 4 concurrent edges
    int c4 = (lane & 15) * 4;        // channel quad

    int e = row_ptr[i];
    int end = row_ptr[i + 1];

    float4 acc = make_float4(0.f, 0.f, 0.f, 0.f);
    float4 acc2 = make_float4(0.f, 0.f, 0.f, 0.f);
    if (q == 0)                      // self term (already *dis[i])
        acc = *reinterpret_cast<const float4*>(&A[(size_t)i * 64 + c4]);

    for (; e + 8 <= end; e += 8) {
        int s0 = csr_src[e + q];
        int s1 = csr_src[e + 4 + q];
        float4 v0 = *reinterpret_cast<const float4*>(&A[(size_t)s0 * 64 + c4]);
        float4 v1 = *reinterpret_cast<const float4*>(&A[(size_t)s1 * 64 + c4]);
        acc.x += v0.x; acc.y += v0.y; acc.z += v0.z; acc.w += v0.w;
        acc2.x += v1.x; acc2.y += v1.y; acc2.z += v1.z; acc2.w += v1.w;
    }
    for (; e + 4 <= end; e += 4) {
        int s = csr_src[e + q];
        float4 v = *reinterpret_cast<const float4*>(&A[(size_t)s * 64 + c4]);
        acc.x += v.x; acc.y += v.y; acc.z += v.z; acc.w += v.w;
    }
    if (e + q < end) {
        int s = csr_src[e + q];
        float4 v = *reinterpret_cast<const float4*>(&A[(size_t)s * 64 + c4]);
        acc2.x += v.x; acc2.y += v.y; acc2.z += v.z; acc2.w += v.w;
    }
    acc.x += acc2.x; acc.y += acc2.y; acc.z += acc2.z; acc.w += acc2.w;

    acc.x += __shfl_xor(acc.x, 16); acc.x += __shfl_xor(acc.x, 32);
    acc.y += __shfl_xor(acc.y, 16); acc.y += __shfl_xor(acc.y, 32);
    acc.z += __shfl_xor(acc.z, 16); acc.z += __shfl_xor(acc.z, 32);
    acc.w += __shfl_xor(acc.w, 16); acc.w += __shfl_xor(acc.w, 32);

    if (q == 0) {
        float d = dis[i];
        float4 o;
        o.x = bias[c4]     + d * acc.x;
        o.y = bias[c4 + 1] + d * acc.y;
        o.z = bias[c4 + 2] + d * acc.z;
        o.w = bias[c4 + 3] + d * acc.w;
        *reinterpret_cast<float4*>(&B[(size_t)i * 64 + c4]) = o;
    }
}

// ---------------------------------------------------------------------------
// pool: batch is sorted -> run-length accumulate per wave (32 nodes/wave)
__global__ __launch_bounds__(256) void pool_kernel(const float* __restrict__ B,
                                                   const int* __restrict__ batch,
                                                   float* __restrict__ sums,
                                                   float* __restrict__ cnt) {
    int w = blockIdx.x * 4 + (threadIdx.x >> 6);
    int lane = threadIdx.x & 63;
    int n0 = w * 32;
    if (n0 >= N_NODES) return;
    int n1 = min(n0 + 32, N_NODES);
    int curg = batch[n0];
    float acc = 0.f;
    int run = 0;
    for (int n = n0; n < n1; ++n) {
        int g = batch[n];
        if (g != curg) {
            atomicAdd(&sums[curg * 64 + lane], acc);
            if (lane == 0) atomicAdd(&cnt[curg], (float)run);
            curg = g; acc = 0.f; run = 0;
        }
        acc += fmaxf(B[(size_t)n * 64 + lane], 0.f);
        run++;
    }
    atomicAdd(&sums[curg * 64 + lane], acc);
    if (lane == 0) atomicAdd(&cnt[curg], (float)run);
}

__global__ __launch_bounds__(256) void final_kernel(const float* __restrict__ sums,
                                                    const float* __restrict__ cnt,
                                                    float* __restrict__ out) {
    int idx = blockIdx.x * 256 + threadIdx.x;
    if (idx < N_GRAPHS * 64) out[idx] = sums[idx] / fmaxf(cnt[idx >> 6], 1.0f);
}

// ---------------------------------------------------------------------------
extern "C" void kernel_launch(void* const* d_in, const int* in_sizes, int n_in,
                              void* d_out, int out_size, void* d_ws, size_t ws_size,
                              hipStream_t stream) {
    const float* x     = (const float*)d_in[0];
    const int*   edge  = (const int*)d_in[1];   // [2, E]: row0 = src, row1 = dst
    const int*   batch = (const int*)d_in[2];
    const float* W1    = (const float*)d_in[3];
    const float* b1    = (const float*)d_in[4];
    const float* W2    = (const float*)d_in[5];
    const float* b2    = (const float*)d_in[6];
    float* out = (float*)d_out;

    // workspace layout
    float* A        = (float*)d_ws;                       // 6,400,000 f (aliases pairs)
    float* B        = A + (size_t)N_NODES * 64;           // 6,400,000 f
    float* dis      = B + (size_t)N_NODES * 64;           // 100,000 f
    float* sums     = dis + N_NODES;                      // 32,768 f
    float* cnt_f    = sums + (size_t)N_GRAPHS * 64;       // 512 f
    int*   row_ptr  = (int*)(cnt_f + N_GRAPHS);           // 100,001 i
    int*   hist_g   = row_ptr + N_NODES + 1;              // NB*NBLK = 305,762 i
    int*   total    = hist_g + NB * NBLK;                 // 391 i
    int*   bbase    = total + NB;                         // 392 i
    int*   csr_src  = bbase + NB + 1;                     // 3,200,000 i
    int2*  pairs    = (int2*)A;                           // aliases A (dead until GEMM1)

    const int* src = edge;
    const int* dst = edge + N_EDGES;

    hipMemsetAsync(sums, 0, (N_GRAPHS * 64 + N_GRAPHS) * sizeof(float), stream);

    // CSR build: binned counting sort, all per-edge atomics in LDS
    binhist_kernel<<<NBLK, 256, 0, stream>>>(dst, hist_g);
    s1_kernel<<<NB, 256, 0, stream>>>(hist_g, total);
    s2_kernel<<<1, 512, 0, stream>>>(total, bbase);
    binscatter_kernel<<<NBLK, 256, 0, stream>>>(src, dst, hist_g, bbase, pairs);
    bucket_csr_kernel<<<NB, 256, 0, stream>>>(pairs, bbase, csr_src, row_ptr, dis);

    // layer 1: A = (x@W1)*dis ; B = b1 + dis*(A[i] + sum A[src])
    gemm_kernel<IN_CH, false><<<(N_NODES + 31) / 32, 256, 0, stream>>>(x, W1, dis, A);
    gather_kernel<<<(N_NODES + 3) / 4, 256, 0, stream>>>(row_ptr, csr_src, dis, b1, A, B);

    // layer 2 (relu fused into GEMM read)
    gemm_kernel<HID, true><<<(N_NODES + 31) / 32, 256, 0, stream>>>(B, W2, dis, A);
    gather_kernel<<<(N_NODES + 3) / 4, 256, 0, stream>>>(row_ptr, csr_src, dis, b2, A, B);

    // pool (relu fused) + finalize
    pool_kernel<<<(N_NODES + 127) / 128, 256, 0, stream>>>(B, batch, sums, cnt_f);
    final_kernel<<<(N_GRAPHS * 64 + 255) / 256, 256, 0, stream>>>(sums, cnt_f, out);
}

// Round 5
// 401.081 us; speedup vs baseline: 4.8406x; 1.1750x over previous
//
#include <hip/hip_runtime.h>

typedef unsigned int uint;

#define N_NODES 100000
#define N_EDGES 3200000
#define IN_CH 128
#define HID 64
#define N_GRAPHS 512
#define EPB 4096                                   // edges per block (binning)
#define NBLK ((N_EDGES + EPB - 1) / EPB)           // 782
#define NB 391                                     // buckets = dst>>8 (256 nodes each)

// ---------------------------------------------------------------------------
// bf16 helpers: A matrices are stored as packed bf16 (uint = 2 channels)
__device__ __forceinline__ uint f2bf1(float f) {
    union { float f; uint i; } v; v.f = f;
    return (v.i + 0x7fffu + ((v.i >> 16) & 1u)) >> 16;    // RNE
}
__device__ __forceinline__ uint pack2(float lo, float hi) {
    return f2bf1(lo) | (f2bf1(hi) << 16);
}
__device__ __forceinline__ void bacc(uint u, float& lo, float& hi) {
    union { uint i; float f; } t0, t1;
    t0.i = u << 16;
    t1.i = u & 0xffff0000u;
    lo += t0.f; hi += t1.f;
}

// ---------------------------------------------------------------------------
// P1: per-block bucket histogram only (LDS, 4 replicated copies). NO global atomics.
__global__ __launch_bounds__(256) void binhist_kernel(const int* __restrict__ dst,
                                                      int* __restrict__ hist_g) {
    __shared__ int h[4 * NB];
    for (int i = threadIdx.x; i < 4 * NB; i += 256) h[i] = 0;
    __syncthreads();
    int w = threadIdx.x >> 6;          // wave id 0..3 -> histogram copy
    int base = blockIdx.x * EPB;
    int end = min(base + EPB, N_EDGES);
    for (int e = base + threadIdx.x; e < end; e += 256)
        atomicAdd(&h[w * NB + (dst[e] >> 8)], 1);
    __syncthreads();
    for (int b = threadIdx.x; b < NB; b += 256)
        hist_g[b * NBLK + blockIdx.x] = h[b] + h[NB + b] + h[2 * NB + b] + h[3 * NB + b];
}

// S1: per bucket, exclusive scan across blocks (in place), total per bucket
__global__ __launch_bounds__(256) void s1_kernel(int* __restrict__ hist_g,
                                                 int* __restrict__ total) {
    __shared__ int buf[NBLK];
    int b = blockIdx.x;
    for (int j = threadIdx.x; j < NBLK; j += 256) buf[j] = hist_g[b * NBLK + j];
    __syncthreads();
    if (threadIdx.x == 0) {
        int run = 0;
        for (int j = 0; j < NBLK; ++j) { int v = buf[j]; buf[j] = run; run += v; }
        total[b] = run;
    }
    __syncthreads();
    for (int j = threadIdx.x; j < NBLK; j += 256) hist_g[b * NBLK + j] = buf[j];
}

// S2: exclusive scan of bucket totals -> bucket bases (bbase has NB+1 entries)
__global__ __launch_bounds__(512) void s2_kernel(const int* __restrict__ total,
                                                 int* __restrict__ bbase) {
    __shared__ int s[512];
    int t = threadIdx.x;
    int v = (t < NB) ? total[t] : 0;
    s[t] = v;
    __syncthreads();
#pragma unroll
    for (int o = 1; o < 512; o <<= 1) {
        int x = (t >= o) ? s[t - o] : 0;
        __syncthreads();
        s[t] += x;
        __syncthreads();
    }
    if (t < NB) bbase[t] = s[t] - v;
    if (t == 0) bbase[NB] = N_EDGES;
}

// P3: multisplit — write packed (dst&255)<<24 | src bucket-contiguously
__global__ __launch_bounds__(256) void binscatter_kernel(const int* __restrict__ src,
                                                         const int* __restrict__ dst,
                                                         const int* __restrict__ hist_g,
                                                         const int* __restrict__ bbase,
                                                         uint* __restrict__ pairs) {
    __shared__ int cur[NB];
    __shared__ int start[NB];
    for (int i = threadIdx.x; i < NB; i += 256) {
        cur[i] = 0;
        start[i] = bbase[i] + hist_g[i * NBLK + blockIdx.x];
    }
    __syncthreads();
    int base = blockIdx.x * EPB;
    int end = min(base + EPB, N_EDGES);
    for (int e = base + threadIdx.x; e < end; e += 256) {
        int s = src[e], d = dst[e];
        int b = d >> 8;
        int r = atomicAdd(&cur[b], 1);
        pairs[start[b] + r] = ((uint)(d & 255) << 24) | (uint)s;   // src < 2^17
    }
}

// P4: fused per-bucket CSR build: LDS histogram -> LDS scan -> row_ptr/dis
//     (plain stores) -> LDS-cursor fill of csr_src (writes within ~32KB window).
__global__ __launch_bounds__(256) void bucket_csr_kernel(const uint* __restrict__ pairs,
                                                         const int* __restrict__ bbase,
                                                         int* __restrict__ csr_src,
                                                         int* __restrict__ row_ptr,
                                                         float* __restrict__ dis) {
    __shared__ int h[256];
    int b = blockIdx.x;
    int t = threadIdx.x;
    int e0 = bbase[b];
    int e1 = bbase[b + 1];
    h[t] = 0;
    __syncthreads();
    for (int e = e0 + t; e < e1; e += 256)
        atomicAdd(&h[pairs[e] >> 24], 1);
    __syncthreads();
    int v = h[t];                       // in-degree of node b*256+t
#pragma unroll
    for (int o = 1; o < 256; o <<= 1) {
        int x = (t >= o) ? h[t - o] : 0;
        __syncthreads();
        h[t] += x;
        __syncthreads();
    }
    int excl = h[t] - v;
    int n = b * 256 + t;
    if (n < N_NODES) {
        row_ptr[n] = e0 + excl;
        dis[n] = rsqrtf((float)v + 1.0f);
    }
    if (b == NB - 1 && t == 0) row_ptr[N_NODES] = N_EDGES;
    __syncthreads();
    h[t] = e0 + excl;                   // cursor
    __syncthreads();
    for (int e = e0 + t; e < e1; e += 256) {
        uint p = pairs[e];
        int pos = atomicAdd(&h[p >> 24], 1);
        csr_src[pos] = (int)(p & 0xFFFFFFu);
    }
}

// ---------------------------------------------------------------------------
// Y[M,64](bf16 packed) = ((RELU?relu(X):X)[M,K] @ W[K,64]) * dis[row]
template<int K, bool RELU>
__global__ __launch_bounds__(256) void gemm_kernel(const float* __restrict__ X,
                                                   const float* __restrict__ W,
                                                   const float* __restrict__ dis,
                                                   uint* __restrict__ Y) {
    __shared__ float Wl[K * 64];
    int t = threadIdx.x;
    for (int idx = t; idx < K * 64; idx += 256) Wl[idx] = W[idx];
    __syncthreads();

    int row = blockIdx.x * 32 + (t >> 3);
    if (row >= N_NODES) return;
    int c0 = (t & 7) * 8;

    float acc[8] = {0.f, 0.f, 0.f, 0.f, 0.f, 0.f, 0.f, 0.f};
    const float* xr = X + (size_t)row * K;
#pragma unroll 8
    for (int k = 0; k < K; k += 4) {
        float4 xv = *reinterpret_cast<const float4*>(xr + k);
        if (RELU) {
            xv.x = fmaxf(xv.x, 0.f); xv.y = fmaxf(xv.y, 0.f);
            xv.z = fmaxf(xv.z, 0.f); xv.w = fmaxf(xv.w, 0.f);
        }
        float xk[4] = {xv.x, xv.y, xv.z, xv.w};
#pragma unroll
        for (int kk = 0; kk < 4; ++kk) {
            const float4 w0 = *reinterpret_cast<const float4*>(&Wl[(k + kk) * 64 + c0]);
            const float4 w1 = *reinterpret_cast<const float4*>(&Wl[(k + kk) * 64 + c0 + 4]);
            acc[0] += xk[kk] * w0.x; acc[1] += xk[kk] * w0.y;
            acc[2] += xk[kk] * w0.z; acc[3] += xk[kk] * w0.w;
            acc[4] += xk[kk] * w1.x; acc[5] += xk[kk] * w1.y;
            acc[6] += xk[kk] * w1.z; acc[7] += xk[kk] * w1.w;
        }
    }
    float d = dis[row];
    uint4 o;
    o.x = pack2(acc[0] * d, acc[1] * d);
    o.y = pack2(acc[2] * d, acc[3] * d);
    o.z = pack2(acc[4] * d, acc[5] * d);
    o.w = pack2(acc[6] * d, acc[7] * d);
    *reinterpret_cast<uint4*>(Y + (size_t)row * 32 + (t & 7) * 4) = o;
}

// ---------------------------------------------------------------------------
// wave per node, 4 edges concurrent (16 lanes/edge, bf16x4 = 8B per lane),
// 8-edge unroll with dual accumulators:
// B[i] = b + dis[i] * (A'[i] + sum A'[src]),  A' = (X@W)*dis  (bf16)
__global__ __launch_bounds__(256) void gather_kernel(const int* __restrict__ row_ptr,
                                                     const int* __restrict__ csr_src,
                                                     const float* __restrict__ dis,
                                                     const float* __restrict__ bias,
                                                     const uint* __restrict__ A,
                                                     float* __restrict__ B) {
    int i = blockIdx.x * 4 + (threadIdx.x >> 6);
    if (i >= N_NODES) return;
    int lane = threadIdx.x & 63;
    int q = lane >> 4;               // which of 4 concurrent edges
    int cu = (lane & 15) * 2;        // uint offset in 32-uint row (4 channels)

    int e = row_ptr[i];
    int end = row_ptr[i + 1];

    float a0 = 0.f, a1 = 0.f, a2 = 0.f, a3 = 0.f;
    float b0 = 0.f, b1 = 0.f, b2 = 0.f, b3 = 0.f;
    if (q == 0) {                    // self term (already *dis[i])
        uint2 u = *reinterpret_cast<const uint2*>(&A[(size_t)i * 32 + cu]);
        bacc(u.x, a0, a1); bacc(u.y, a2, a3);
    }
    for (; e + 8 <= end; e += 8) {
        int s0 = csr_src[e + q];
        int s1 = csr_src[e + 4 + q];
        uint2 u0 = *reinterpret_cast<const uint2*>(&A[(size_t)s0 * 32 + cu]);
        uint2 u1 = *reinterpret_cast<const uint2*>(&A[(size_t)s1 * 32 + cu]);
        bacc(u0.x, a0, a1); bacc(u0.y, a2, a3);
        bacc(u1.x, b0, b1); bacc(u1.y, b2, b3);
    }
    for (; e + 4 <= end; e += 4) {
        int s = csr_src[e + q];
        uint2 u = *reinterpret_cast<const uint2*>(&A[(size_t)s * 32 + cu]);
        bacc(u.x, a0, a1); bacc(u.y, a2, a3);
    }
    if (e + q < end) {
        int s = csr_src[e + q];
        uint2 u = *reinterpret_cast<const uint2*>(&A[(size_t)s * 32 + cu]);
        bacc(u.x, b0, b1); bacc(u.y, b2, b3);
    }
    a0 += b0; a1 += b1; a2 += b2; a3 += b3;

    a0 += __shfl_xor(a0, 16); a0 += __shfl_xor(a0, 32);
    a1 += __shfl_xor(a1, 16); a1 += __shfl_xor(a1, 32);
    a2 += __shfl_xor(a2, 16); a2 += __shfl_xor(a2, 32);
    a3 += __shfl_xor(a3, 16); a3 += __shfl_xor(a3, 32);

    if (q == 0) {
        int c4 = (lane & 15) * 4;
        float d = dis[i];
        float4 o;
        o.x = bias[c4]     + d * a0;
        o.y = bias[c4 + 1] + d * a1;
        o.z = bias[c4 + 2] + d * a2;
        o.w = bias[c4 + 3] + d * a3;
        *reinterpret_cast<float4*>(&B[(size_t)i * 64 + c4]) = o;
    }
}

// ---------------------------------------------------------------------------
// pool: batch is sorted -> run-length accumulate per wave (32 nodes/wave)
__global__ __launch_bounds__(256) void pool_kernel(const float* __restrict__ B,
                                                   const int* __restrict__ batch,
                                                   float* __restrict__ sums,
                                                   float* __restrict__ cnt) {
    int w = blockIdx.x * 4 + (threadIdx.x >> 6);
    int lane = threadIdx.x & 63;
    int n0 = w * 32;
    if (n0 >= N_NODES) return;
    int n1 = min(n0 + 32, N_NODES);
    int curg = batch[n0];
    float acc = 0.f;
    int run = 0;
    for (int n = n0; n < n1; ++n) {
        int g = batch[n];
        if (g != curg) {
            atomicAdd(&sums[curg * 64 + lane], acc);
            if (lane == 0) atomicAdd(&cnt[curg], (float)run);
            curg = g; acc = 0.f; run = 0;
        }
        acc += fmaxf(B[(size_t)n * 64 + lane], 0.f);
        run++;
    }
    atomicAdd(&sums[curg * 64 + lane], acc);
    if (lane == 0) atomicAdd(&cnt[curg], (float)run);
}

__global__ __launch_bounds__(256) void final_kernel(const float* __restrict__ sums,
                                                    const float* __restrict__ cnt,
                                                    float* __restrict__ out) {
    int idx = blockIdx.x * 256 + threadIdx.x;
    if (idx < N_GRAPHS * 64) out[idx] = sums[idx] / fmaxf(cnt[idx >> 6], 1.0f);
}

// ---------------------------------------------------------------------------
extern "C" void kernel_launch(void* const* d_in, const int* in_sizes, int n_in,
                              void* d_out, int out_size, void* d_ws, size_t ws_size,
                              hipStream_t stream) {
    const float* x     = (const float*)d_in[0];
    const int*   edge  = (const int*)d_in[1];   // [2, E]: row0 = src, row1 = dst
    const int*   batch = (const int*)d_in[2];
    const float* W1    = (const float*)d_in[3];
    const float* b1    = (const float*)d_in[4];
    const float* W2    = (const float*)d_in[5];
    const float* b2    = (const float*)d_in[6];
    float* out = (float*)d_out;

    // workspace layout
    uint*  A        = (uint*)d_ws;                        // 3,200,000 u (bf16 A; aliases pairs)
    float* B        = (float*)(A + (size_t)N_NODES * 32); // 6,400,000 f
    float* dis      = B + (size_t)N_NODES * 64;           // 100,000 f
    float* sums     = dis + N_NODES;                      // 32,768 f
    float* cnt_f    = sums + (size_t)N_GRAPHS * 64;       // 512 f
    int*   row_ptr  = (int*)(cnt_f + N_GRAPHS);           // 100,001 i
    int*   hist_g   = row_ptr + N_NODES + 1;              // NB*NBLK = 305,762 i
    int*   total    = hist_g + NB * NBLK;                 // 391 i
    int*   bbase    = total + NB;                         // 392 i
    int*   csr_src  = bbase + NB + 1;                     // 3,200,000 i
    uint*  pairs    = A;                                  // aliases A (dead until GEMM1)

    const int* src = edge;
    const int* dst = edge + N_EDGES;

    hipMemsetAsync(sums, 0, (N_GRAPHS * 64 + N_GRAPHS) * sizeof(float), stream);

    // CSR build: binned counting sort, all per-edge atomics in LDS
    binhist_kernel<<<NBLK, 256, 0, stream>>>(dst, hist_g);
    s1_kernel<<<NB, 256, 0, stream>>>(hist_g, total);
    s2_kernel<<<1, 512, 0, stream>>>(total, bbase);
    binscatter_kernel<<<NBLK, 256, 0, stream>>>(src, dst, hist_g, bbase, pairs);
    bucket_csr_kernel<<<NB, 256, 0, stream>>>(pairs, bbase, csr_src, row_ptr, dis);

    // layer 1: A = bf16((x@W1)*dis) ; B = b1 + dis*(A[i] + sum A[src])
    gemm_kernel<IN_CH, false><<<(N_NODES + 31) / 32, 256, 0, stream>>>(x, W1, dis, A);
    gather_kernel<<<(N_NODES + 3) / 4, 256, 0, stream>>>(row_ptr, csr_src, dis, b1, A, B);

    // layer 2 (relu fused into GEMM read)
    gemm_kernel<HID, true><<<(N_NODES + 31) / 32, 256, 0, stream>>>(B, W2, dis, A);
    gather_kernel<<<(N_NODES + 3) / 4, 256, 0, stream>>>(row_ptr, csr_src, dis, b2, A, B);

    // pool (relu fused) + finalize
    pool_kernel<<<(N_NODES + 127) / 128, 256, 0, stream>>>(B, batch, sums, cnt_f);
    final_kernel<<<(N_GRAPHS * 64 + 255) / 256, 256, 0, stream>>>(sums, cnt_f, out);
}

// Round 6
// 370.229 us; speedup vs baseline: 5.2440x; 1.0833x over previous
//
#include <hip/hip_runtime.h>

typedef unsigned int uint;

#define N_NODES 100000
#define N_EDGES 3200000
#define IN_CH 128
#define HID 64
#define N_GRAPHS 512
#define EPB 4096                                   // edges per block (binning)
#define NBLK ((N_EDGES + EPB - 1) / EPB)           // 782
#define NB 391                                     // buckets = dst>>8 (256 nodes each)
#define CAP 10240                                  // bucket capacity (mean 8192, 22 sigma)

// ---------------------------------------------------------------------------
// bf16 helpers: A matrices are stored as packed bf16 (uint = 2 channels)
__device__ __forceinline__ uint f2bf1(float f) {
    union { float f; uint i; } v; v.f = f;
    return (v.i + 0x7fffu + ((v.i >> 16) & 1u)) >> 16;    // RNE
}
__device__ __forceinline__ uint pack2(float lo, float hi) {
    return f2bf1(lo) | (f2bf1(hi) << 16);
}
__device__ __forceinline__ void bacc(uint u, float& lo, float& hi) {
    union { uint i; float f; } t0, t1;
    t0.i = u << 16;
    t1.i = u & 0xffff0000u;
    lo += t0.f; hi += t1.f;
}

// ---------------------------------------------------------------------------
// One-pass multisplit: edges cached in registers, LDS histogram, one padded
// global atomic per (bucket, block) reserves the range, scatter from registers.
// bcnt[b*16] ends up = bucket edge count.
__global__ __launch_bounds__(256) void scatter_kernel(const int* __restrict__ src,
                                                      const int* __restrict__ dst,
                                                      int* __restrict__ bcnt,
                                                      uint* __restrict__ pairs) {
    __shared__ int h[4 * NB];
    __shared__ int start[NB];
    __shared__ int cur[NB];
    int t = threadIdx.x;
    int base = blockIdx.x * EPB;

    int rs[16], rd[16];
#pragma unroll
    for (int j = 0; j < 16; ++j) {
        int e = base + j * 256 + t;
        if (e < N_EDGES) { rs[j] = src[e]; rd[j] = dst[e]; }
        else rd[j] = -1;
    }
    for (int i = t; i < 4 * NB; i += 256) h[i] = 0;
    __syncthreads();
    int w = t >> 6;
#pragma unroll
    for (int j = 0; j < 16; ++j)
        if (rd[j] >= 0) atomicAdd(&h[w * NB + (rd[j] >> 8)], 1);
    __syncthreads();
    for (int b = t; b < NB; b += 256) {
        int tot = h[b] + h[NB + b] + h[2 * NB + b] + h[3 * NB + b];
        start[b] = tot ? atomicAdd(&bcnt[b * 16], tot) : 0;
        cur[b] = 0;
    }
    __syncthreads();
#pragma unroll
    for (int j = 0; j < 16; ++j) {
        if (rd[j] >= 0) {
            int b = rd[j] >> 8;
            int r = atomicAdd(&cur[b], 1);
            pairs[(size_t)b * CAP + start[b] + r] =
                ((uint)(rd[j] & 255) << 24) | (uint)rs[j];   // src < 2^17
        }
    }
}

// ---------------------------------------------------------------------------
// Per-bucket CSR build: LDS histogram -> scan -> rstart/rend/dis (plain stores)
// -> LDS-cursor fill of csr_src (writes within a 40KB window).
__global__ __launch_bounds__(256) void bucket_csr_kernel(const uint* __restrict__ pairs,
                                                         const int* __restrict__ bcnt,
                                                         int* __restrict__ csr_src,
                                                         int* __restrict__ rstart,
                                                         int* __restrict__ rend,
                                                         float* __restrict__ dis) {
    __shared__ int h[256];
    int b = blockIdx.x;
    int t = threadIdx.x;
    int e0 = b * CAP;
    int e1 = e0 + bcnt[b * 16];
    h[t] = 0;
    __syncthreads();
    for (int e = e0 + t; e < e1; e += 256)
        atomicAdd(&h[pairs[e] >> 24], 1);
    __syncthreads();
    int v = h[t];                       // in-degree of node b*256+t
#pragma unroll
    for (int o = 1; o < 256; o <<= 1) {
        int x = (t >= o) ? h[t - o] : 0;
        __syncthreads();
        h[t] += x;
        __syncthreads();
    }
    int excl = h[t] - v;
    int n = b * 256 + t;
    if (n < N_NODES) {
        rstart[n] = e0 + excl;
        rend[n] = e0 + excl + v;
        dis[n] = rsqrtf((float)v + 1.0f);
    }
    __syncthreads();
    h[t] = e0 + excl;                   // cursor
    __syncthreads();
    for (int e = e0 + t; e < e1; e += 256) {
        uint p = pairs[e];
        int pos = atomicAdd(&h[p >> 24], 1);
        csr_src[pos] = (int)(p & 0xFFFFFFu);
    }
}

// ---------------------------------------------------------------------------
// Y[M,64](bf16 packed) = ((RELU?relu(X):X)[M,K] @ W[K,64]) * dis[row]
// block: 128 rows x 64 ch; thread: 4 rows x 8 ch. W + 32-k X chunk in LDS,
// all inner-loop LDS reads are wave-broadcast (8 distinct addresses).
template<int K, bool RELU>
__global__ __launch_bounds__(256) void gemm_kernel(const float* __restrict__ X,
                                                   const float* __restrict__ W,
                                                   const float* __restrict__ dis,
                                                   uint* __restrict__ Y) {
    __shared__ float Wl[K * 64];
    __shared__ float Xs[128 * 33];      // 32-k chunk, ld 33 (bank-conflict pad)
    int t = threadIdx.x;
    for (int idx = t; idx < K * 64; idx += 256) Wl[idx] = W[idx];

    int r0 = (t >> 3) * 4;              // thread's first row (0..124)
    int c0 = (t & 7) * 8;               // thread's first channel
    int rowBase = blockIdx.x * 128;

    float acc[4][8];
#pragma unroll
    for (int a = 0; a < 4; ++a)
#pragma unroll
        for (int c = 0; c < 8; ++c) acc[a][c] = 0.f;

    int srow = t >> 1;                  // staging: 2 threads per row
    int shh = (t & 1) * 16;
    bool sok = (rowBase + srow) < N_NODES;
    const float* xbase = X + (size_t)(rowBase + srow) * K + shh;

    for (int kc = 0; kc < K; kc += 32) {
        __syncthreads();
        // stage Xs[128][32]: 16 floats per thread
#pragma unroll
        for (int f = 0; f < 4; ++f) {
            float4 v = sok ? *reinterpret_cast<const float4*>(xbase + kc + f * 4)
                           : make_float4(0.f, 0.f, 0.f, 0.f);
            if (RELU) {
                v.x = fmaxf(v.x, 0.f); v.y = fmaxf(v.y, 0.f);
                v.z = fmaxf(v.z, 0.f); v.w = fmaxf(v.w, 0.f);
            }
            int o = srow * 33 + shh + f * 4;
            Xs[o] = v.x; Xs[o + 1] = v.y; Xs[o + 2] = v.z; Xs[o + 3] = v.w;
        }
        __syncthreads();
#pragma unroll
        for (int kk = 0; kk < 32; ++kk) {
            const float4 wa = *reinterpret_cast<const float4*>(&Wl[(kc + kk) * 64 + c0]);
            const float4 wb = *reinterpret_cast<const float4*>(&Wl[(kc + kk) * 64 + c0 + 4]);
            float xr[4];
#pragma unroll
            for (int a = 0; a < 4; ++a) xr[a] = Xs[(r0 + a) * 33 + kk];
#pragma unroll
            for (int a = 0; a < 4; ++a) {
                acc[a][0] += xr[a] * wa.x; acc[a][1] += xr[a] * wa.y;
                acc[a][2] += xr[a] * wa.z; acc[a][3] += xr[a] * wa.w;
                acc[a][4] += xr[a] * wb.x; acc[a][5] += xr[a] * wb.y;
                acc[a][6] += xr[a] * wb.z; acc[a][7] += xr[a] * wb.w;
            }
        }
    }
#pragma unroll
    for (int a = 0; a < 4; ++a) {
        int row = rowBase + r0 + a;
        if (row < N_NODES) {
            float d = dis[row];
            uint4 o;
            o.x = pack2(acc[a][0] * d, acc[a][1] * d);
            o.y = pack2(acc[a][2] * d, acc[a][3] * d);
            o.z = pack2(acc[a][4] * d, acc[a][5] * d);
            o.w = pack2(acc[a][6] * d, acc[a][7] * d);
            *reinterpret_cast<uint4*>(Y + (size_t)row * 32 + (t & 7) * 4) = o;
        }
    }
}

// ---------------------------------------------------------------------------
// wave per node, 8 edges concurrent (8 lanes/edge, bf16x8 = 16B per lane),
// 16-edge unroll with dual accumulators:
// B[i] = bias + dis[i] * (A'[i] + sum A'[src]),  A' = (X@W)*dis  (bf16)
__global__ __launch_bounds__(256) void gather_kernel(const int* __restrict__ rstart,
                                                     const int* __restrict__ rend,
                                                     const int* __restrict__ csr_src,
                                                     const float* __restrict__ dis,
                                                     const float* __restrict__ bias,
                                                     const uint* __restrict__ A,
                                                     float* __restrict__ B) {
    int i = blockIdx.x * 4 + (threadIdx.x >> 6);
    if (i >= N_NODES) return;
    int lane = threadIdx.x & 63;
    int q = lane >> 3;               // which of 8 concurrent edges
    int cu = (lane & 7) * 4;         // uint4 offset in 32-uint row (8 channels)

    // preload bias (epilogue regs)
    float4 bi0 = *reinterpret_cast<const float4*>(&bias[(lane & 7) * 8]);
    float4 bi1 = *reinterpret_cast<const float4*>(&bias[(lane & 7) * 8 + 4]);

    int e = rstart[i];
    int end = rend[i];

    float a[8], b[8];
#pragma unroll
    for (int j = 0; j < 8; ++j) { a[j] = 0.f; b[j] = 0.f; }

    if (q == 0) {                    // self term (already *dis[i])
        uint4 u = *reinterpret_cast<const uint4*>(&A[(size_t)i * 32 + cu]);
        bacc(u.x, a[0], a[1]); bacc(u.y, a[2], a[3]);
        bacc(u.z, a[4], a[5]); bacc(u.w, a[6], a[7]);
    }
    for (; e + 16 <= end; e += 16) {
        int s0 = csr_src[e + q];
        int s1 = csr_src[e + 8 + q];
        uint4 u0 = *reinterpret_cast<const uint4*>(&A[(size_t)s0 * 32 + cu]);
        uint4 u1 = *reinterpret_cast<const uint4*>(&A[(size_t)s1 * 32 + cu]);
        bacc(u0.x, a[0], a[1]); bacc(u0.y, a[2], a[3]);
        bacc(u0.z, a[4], a[5]); bacc(u0.w, a[6], a[7]);
        bacc(u1.x, b[0], b[1]); bacc(u1.y, b[2], b[3]);
        bacc(u1.z, b[4], b[5]); bacc(u1.w, b[6], b[7]);
    }
    for (; e + 8 <= end; e += 8) {
        int s = csr_src[e + q];
        uint4 u = *reinterpret_cast<const uint4*>(&A[(size_t)s * 32 + cu]);
        bacc(u.x, a[0], a[1]); bacc(u.y, a[2], a[3]);
        bacc(u.z, a[4], a[5]); bacc(u.w, a[6], a[7]);
    }
    if (e + q < end) {
        int s = csr_src[e + q];
        uint4 u = *reinterpret_cast<const uint4*>(&A[(size_t)s * 32 + cu]);
        bacc(u.x, b[0], b[1]); bacc(u.y, b[2], b[3]);
        bacc(u.z, b[4], b[5]); bacc(u.w, b[6], b[7]);
    }
#pragma unroll
    for (int j = 0; j < 8; ++j) {
        a[j] += b[j];
        a[j] += __shfl_xor(a[j], 8);
        a[j] += __shfl_xor(a[j], 16);
        a[j] += __shfl_xor(a[j], 32);
    }
    if (q == 0) {
        float d = dis[i];
        float* br = B + (size_t)i * 64 + (lane & 7) * 8;
        *reinterpret_cast<float4*>(br) =
            make_float4(bi0.x + d * a[0], bi0.y + d * a[1],
                        bi0.z + d * a[2], bi0.w + d * a[3]);
        *reinterpret_cast<float4*>(br + 4) =
            make_float4(bi1.x + d * a[4], bi1.y + d * a[5],
                        bi1.z + d * a[6], bi1.w + d * a[7]);
    }
}

// ---------------------------------------------------------------------------
// pool: batch is sorted -> run-length accumulate per wave (32 nodes/wave)
__global__ __launch_bounds__(256) void pool_kernel(const float* __restrict__ B,
                                                   const int* __restrict__ batch,
                                                   float* __restrict__ sums,
                                                   float* __restrict__ cnt) {
    int w = blockIdx.x * 4 + (threadIdx.x >> 6);
    int lane = threadIdx.x & 63;
    int n0 = w * 32;
    if (n0 >= N_NODES) return;
    int n1 = min(n0 + 32, N_NODES);
    int curg = batch[n0];
    float acc = 0.f;
    int run = 0;
    for (int n = n0; n < n1; ++n) {
        int g = batch[n];
        if (g != curg) {
            atomicAdd(&sums[curg * 64 + lane], acc);
            if (lane == 0) atomicAdd(&cnt[curg], (float)run);
            curg = g; acc = 0.f; run = 0;
        }
        acc += fmaxf(B[(size_t)n * 64 + lane], 0.f);
        run++;
    }
    atomicAdd(&sums[curg * 64 + lane], acc);
    if (lane == 0) atomicAdd(&cnt[curg], (float)run);
}

__global__ __launch_bounds__(256) void final_kernel(const float* __restrict__ sums,
                                                    const float* __restrict__ cnt,
                                                    float* __restrict__ out) {
    int idx = blockIdx.x * 256 + threadIdx.x;
    if (idx < N_GRAPHS * 64) out[idx] = sums[idx] / fmaxf(cnt[idx >> 6], 1.0f);
}

// ---------------------------------------------------------------------------
extern "C" void kernel_launch(void* const* d_in, const int* in_sizes, int n_in,
                              void* d_out, int out_size, void* d_ws, size_t ws_size,
                              hipStream_t stream) {
    const float* x     = (const float*)d_in[0];
    const int*   edge  = (const int*)d_in[1];   // [2, E]: row0 = src, row1 = dst
    const int*   batch = (const int*)d_in[2];
    const float* W1    = (const float*)d_in[3];
    const float* b1    = (const float*)d_in[4];
    const float* W2    = (const float*)d_in[5];
    const float* b2    = (const float*)d_in[6];
    float* out = (float*)d_out;

    // workspace layout (elements)
    uint*  A        = (uint*)d_ws;                        // 3,200,000 u (bf16 A)
    int*   csr_src  = (int*)(A + (size_t)N_NODES * 32);   // NB*CAP = 4,003,840 i
    float* dis      = (float*)(csr_src + NB * CAP);       // 100,000 f
    int*   rstart   = (int*)(dis + N_NODES);              // 100,000 i
    int*   rend     = rstart + N_NODES;                   // 100,000 i
    float* sums     = (float*)(rend + N_NODES);           // 32,768 f
    float* cnt_f    = sums + (size_t)N_GRAPHS * 64;       // 512 f
    int*   bcnt     = (int*)(cnt_f + N_GRAPHS);           // NB*16 = 6,256 i (padded)
    float* B        = (float*)(bcnt + NB * 16);           // 6,400,000 f
    uint*  pairs    = (uint*)B;                           // NB*CAP, aliases B

    const int* src = edge;
    const int* dst = edge + N_EDGES;

    // zero sums + cnt + bcnt in one shot (contiguous)
    hipMemsetAsync(sums, 0, (N_GRAPHS * 64 + N_GRAPHS + NB * 16) * sizeof(float), stream);

    // CSR build: one-pass multisplit + per-bucket local fill
    scatter_kernel<<<NBLK, 256, 0, stream>>>(src, dst, bcnt, pairs);
    bucket_csr_kernel<<<NB, 256, 0, stream>>>(pairs, bcnt, csr_src, rstart, rend, dis);

    // layer 1: A = bf16((x@W1)*dis) ; B = b1 + dis*(A[i] + sum A[src])
    gemm_kernel<IN_CH, false><<<(N_NODES + 127) / 128, 256, 0, stream>>>(x, W1, dis, A);
    gather_kernel<<<(N_NODES + 3) / 4, 256, 0, stream>>>(rstart, rend, csr_src, dis, b1, A, B);

    // layer 2 (relu fused into GEMM read)
    gemm_kernel<HID, true><<<(N_NODES + 127) / 128, 256, 0, stream>>>(B, W2, dis, A);
    gather_kernel<<<(N_NODES + 3) / 4, 256, 0, stream>>>(rstart, rend, csr_src, dis, b2, A, B);

    // pool (relu fused) + finalize
    pool_kernel<<<(N_NODES + 127) / 128, 256, 0, stream>>>(B, batch, sums, cnt_f);
    final_kernel<<<(N_GRAPHS * 64 + 255) / 256, 256, 0, stream>>>(sums, cnt_f, out);
}